// Round 6
// baseline (462.448 us; speedup 1.0000x reference)
//
#include <hip/hip_runtime.h>
#include <hip/hip_bf16.h>
#include <math.h>

#define VV 50000
#define EE 300
#define HD 256
#define BB 256
#define TT 64
#define NEGV -1e9f

// ws layout (floats):
#define OFF_H    0         // [2 buf][2 dir][B][HD]      262144
#define OFF_C    262144    // fallback C-state; full path: padded barrier ctrs
#define OFF_CTR  262144    // [64 chains][32 u32] (128 B stride)  2048 u32
#define OFF_B2   393216    // [2 dir][1024] gate-interleaved bias   2048
#define OFF_WHH  395264    // [dir][256 k][1024 jg] fp32          524288
#define OFF_WIHB 919552    // bf16 [2048 n][320 k] = 327680 floats
#define OFF_ZX   1574912   // [(b*64+t)][2048] fp32               33554432
#define WS_FULL_BYTES ((35129344ULL + 64ULL) * 4ULL)

typedef __attribute__((ext_vector_type(8))) short bf16x8;
typedef __attribute__((ext_vector_type(16))) float f32x16;

__device__ __forceinline__ float sigf(float x) {
  return 1.f / (1.f + __expf(-x));
}
__device__ __forceinline__ float tanhfast(float x) {
  return 1.f - 2.f / (__expf(2.f * x) + 1.f);
}
__device__ __forceinline__ unsigned short f2bf(float f) {
  union { float f; unsigned u; } x;
  x.f = f;
  unsigned r = x.u + 0x7fffu + ((x.u >> 16) & 1u);
  return (unsigned short)(r >> 16);
}

// ---------------- full-path prep: one kernel does everything ---------------
// idx space 655360 (2560 blocks x 256):
//   idx < 131072 : zero H buf0 (both dirs)
//   idx < 2048   : zero barrier counters (u32) + build gate-interleaved bias
//   idx < 524288 : W_hh transpose -> [dir][k][j*4+g] fp32
//   idx < 655360 : W_ih -> bf16 [n=dir*1024+j*4+g][k(320 pad)]
__global__ __launch_bounds__(256) void prep_all(
    const float* __restrict__ whf, const float* __restrict__ whb,
    const float* __restrict__ wif, const float* __restrict__ wib,
    const float* __restrict__ bf, const float* __restrict__ bb,
    float* __restrict__ ws) {
  int idx = blockIdx.x * 256 + threadIdx.x;
  if (idx < 131072) ws[OFF_H + idx] = 0.f;
  if (idx < 2048) {
    ((unsigned int*)(ws + OFF_CTR))[idx] = 0u;
    int dir = idx >> 10, jg = idx & 1023, j = jg >> 2, g = jg & 3;
    ws[OFF_B2 + idx] = (dir ? bb : bf)[g * HD + j];
  }
  if (idx < 524288) {
    int dir = idx >> 18, r = idx & 262143, k = r >> 10, jg = r & 1023;
    int j = jg >> 2, g = jg & 3;
    const float* W = dir ? whb : whf;
    ws[OFF_WHH + idx] = W[(size_t)((g << 8) + j) * HD + k];
  }
  if (idx < 655360) {
    int n = idx / 320, k = idx - n * 320;
    int dir = n >> 10, jg = n & 1023, j = jg >> 2, g = jg & 3;
    float v = 0.f;
    if (k < EE) {
      const float* W = dir ? wib : wif;
      v = W[(size_t)((g << 8) + j) * EE + k];
    }
    ((unsigned short*)(ws + OFF_WIHB))[idx] = f2bf(v);
  }
}

// ---------------- fallback init ---------------------------------------------
__global__ __launch_bounds__(256) void init_kernel(float* __restrict__ ws,
                                                   float* __restrict__ out) {
  int idx = blockIdx.x * 256 + threadIdx.x;
  if (idx < 393216) ws[idx] = 0.f;
  if (idx < BB * 2 * HD) out[idx] = NEGV;
}

// ---------------- Zx = X @ WihT via bf16 MFMA 32x32x16 ---------------------
// block 256 thr = 4 waves (2m x 2n), tile 64m x 128n, K-chunks of 64 (5).
// LDS tiles [row][64 k] bf16, 16B-chunk XOR swizzle: g' = g ^ (row&7).
__global__ __launch_bounds__(256) void zx_mfma(const int* __restrict__ tok,
                                               const float* __restrict__ emb,
                                               float* __restrict__ ws) {
  __shared__ __align__(16) unsigned short a_sm[64 * 64];
  __shared__ __align__(16) unsigned short b_sm[128 * 64];
  const int tid = threadIdx.x;
  const int m0 = blockIdx.x * 64;
  const int n0 = blockIdx.y * 128;
  const unsigned short* wihb = (const unsigned short*)(ws + OFF_WIHB);
  float* zx = ws + OFF_ZX;
  const int lane = tid & 63;
  const int wv = tid >> 6;
  const int wm = wv >> 1, wn = wv & 1;

  f32x16 acc0, acc1;
#pragma unroll
  for (int i = 0; i < 16; ++i) { acc0[i] = 0.f; acc1[i] = 0.f; }

  const int sm_row = tid >> 2;
  const int sq = tid & 3;
  const int tokv = tok[m0 + sm_row];
  const float* er = emb + (size_t)tokv * EE;
  const int bn = tid >> 1;
  const int bq = tid & 1;
  const unsigned short* bsrc = wihb + (size_t)(n0 + bn) * 320 + bq * 32;

  const int fm = wm * 32 + (lane & 31);
  const int koc = lane >> 5;
  const int fnb = wn * 64 + (lane & 31);

  for (int kc = 0; kc < 5; ++kc) {
    const int k0 = kc * 64;
    {
      union { unsigned short u[8]; uint4 v; } pk;
#pragma unroll
      for (int c = 0; c < 2; ++c) {
#pragma unroll
        for (int e = 0; e < 8; ++e) {
          int k = k0 + sq * 16 + c * 8 + e;
          pk.u[e] = (k < EE) ? f2bf(er[k]) : (unsigned short)0;
        }
        int g = sq * 2 + c;
        int gs = g ^ (sm_row & 7);
        *(uint4*)&a_sm[sm_row * 64 + gs * 8] = pk.v;
      }
    }
    {
      const unsigned short* s = bsrc + k0;
#pragma unroll
      for (int c = 0; c < 4; ++c) {
        int g = bq * 4 + c;
        int gs = g ^ (bn & 7);
        *(uint4*)&b_sm[bn * 64 + gs * 8] = *(const uint4*)(s + c * 8);
      }
    }
    __syncthreads();
    bf16x8 afr[4];
#pragma unroll
    for (int ks = 0; ks < 4; ++ks) {
      int gs = (ks * 2 + koc) ^ (fm & 7);
      afr[ks] = *(const bf16x8*)&a_sm[fm * 64 + gs * 8];
    }
#pragma unroll
    for (int nf = 0; nf < 2; ++nf) {
      int n = fnb + nf * 32;
#pragma unroll
      for (int ks = 0; ks < 4; ++ks) {
        int gs = (ks * 2 + koc) ^ (n & 7);
        bf16x8 bfr = *(const bf16x8*)&b_sm[n * 64 + gs * 8];
        if (nf == 0)
          acc0 = __builtin_amdgcn_mfma_f32_32x32x16_bf16(afr[ks], bfr, acc0, 0, 0, 0);
        else
          acc1 = __builtin_amdgcn_mfma_f32_32x32x16_bf16(afr[ks], bfr, acc1, 0, 0, 0);
      }
    }
    __syncthreads();
  }
#pragma unroll
  for (int nf = 0; nf < 2; ++nf) {
#pragma unroll
    for (int r = 0; r < 16; ++r) {
      float v = (nf == 0) ? acc0[r] : acc1[r];
      int row = (r & 3) + 8 * (r >> 2) + 4 * (lane >> 5);
      int m = m0 + wm * 32 + row;
      int n = n0 + wn * 64 + nf * 32 + (lane & 31);
      zx[(size_t)m * 2048 + n] = v;
    }
  }
}

// ---------------- persistent recurrence: W register-stationary -------------
// grid = (32 bgroup, 4 slice, 2 dir) x 512 threads, 1 block/CU.
// waves_per_eu(2,2): cap occupancy at 2 waves/SIMD -> 256-VGPR budget so the
// 128-VGPR W slice stays resident (round-5's 120-VGPR alloc = spilled W).
__global__ __launch_bounds__(512)
__attribute__((amdgpu_waves_per_eu(2, 2))) void lstm_persist(
    const int* __restrict__ lens, float* __restrict__ ws,
    float* __restrict__ out) {
  const int g = blockIdx.x;      // 0..31
  const int slice = blockIdx.y;  // 0..3
  const int dir = blockIdx.z;    // 0..1
  const int tid = threadIdx.x;
  const int wv = tid >> 6;
  const int ln = tid & 63;

  __shared__ float h_sm[8][256];
  __shared__ float red_sm[8][2048];

  // W slice into registers: w[k] = Whh_t[dir][wv*32+k][slice*256 + ln*4 ..+3]
  float4 w[32];
  {
    const float* wp = ws + OFF_WHH + (size_t)dir * 262144 +
                      (size_t)(wv * 32) * 1024 + slice * 256 + ln * 4;
#pragma unroll
    for (int k = 0; k < 32; ++k) w[k] = *(const float4*)(wp + (size_t)k * 1024);
  }
  const int brow = g * 8 + wv;
  const int len = lens[brow];
  const float4 bias =
      *(const float4*)(ws + OFF_B2 + dir * 1024 + slice * 256 + ln * 4);
  float c = 0.f, omax = NEGV;
  unsigned int* ctr =
      (unsigned int*)(ws + OFF_CTR) + (size_t)(dir * 32 + g) * 32;
  const float* zx = ws + OFF_ZX;
  float* hb = ws + OFF_H;  // [2 buf][2 dir][256 b][256 j]
  const int j = slice * 64 + ln;
  const size_t zxbase = (size_t)brow * TT;
  const int zxoff = dir * 1024 + slice * 256 + ln * 4;

  float4 zx4 = *(const float4*)(zx + (zxbase + (dir ? TT - 1 : 0)) * 2048 + zxoff);

  for (int s = 0; s < TT; ++s) {
    const int t = dir ? (TT - 1 - s) : s;
    // stage h(s) from buf s&1 via coherent point loads (2x u64 per thread)
    {
      const float* src =
          hb + (size_t)((((s & 1) * 2 + dir) * 256) + g * 8 + wv) * 256 + ln * 4;
      const unsigned long long* s8 = (const unsigned long long*)src;
      unsigned long long u0 =
          __hip_atomic_load(s8 + 0, __ATOMIC_RELAXED, __HIP_MEMORY_SCOPE_AGENT);
      unsigned long long u1 =
          __hip_atomic_load(s8 + 1, __ATOMIC_RELAXED, __HIP_MEMORY_SCOPE_AGENT);
      float2 f0, f1;
      __builtin_memcpy(&f0, &u0, 8);
      __builtin_memcpy(&f1, &u1, 8);
      h_sm[wv][ln * 4 + 0] = f0.x;
      h_sm[wv][ln * 4 + 1] = f0.y;
      h_sm[wv][ln * 4 + 2] = f1.x;
      h_sm[wv][ln * 4 + 3] = f1.y;
    }
    __syncthreads();
    // FMA over k window [wv*32, wv*32+32), row-pairs to limit liveness
    float4 acc[8];
#pragma unroll
    for (int r = 0; r < 8; ++r) acc[r] = make_float4(0.f, 0.f, 0.f, 0.f);
#pragma unroll
    for (int kq = 0; kq < 8; ++kq) {
#pragma unroll
      for (int rp = 0; rp < 4; ++rp) {
        float4 h0 = *(const float4*)&h_sm[rp * 2 + 0][wv * 32 + kq * 4];
        float4 h1 = *(const float4*)&h_sm[rp * 2 + 1][wv * 32 + kq * 4];
#pragma unroll
        for (int kk = 0; kk < 4; ++kk) {
          float hv0 = kk == 0 ? h0.x : kk == 1 ? h0.y : kk == 2 ? h0.z : h0.w;
          float hv1 = kk == 0 ? h1.x : kk == 1 ? h1.y : kk == 2 ? h1.z : h1.w;
          float4 wk = w[kq * 4 + kk];
          acc[rp * 2 + 0].x += hv0 * wk.x;
          acc[rp * 2 + 0].y += hv0 * wk.y;
          acc[rp * 2 + 0].z += hv0 * wk.z;
          acc[rp * 2 + 0].w += hv0 * wk.w;
          acc[rp * 2 + 1].x += hv1 * wk.x;
          acc[rp * 2 + 1].y += hv1 * wk.y;
          acc[rp * 2 + 1].z += hv1 * wk.z;
          acc[rp * 2 + 1].w += hv1 * wk.w;
        }
      }
    }
#pragma unroll
    for (int r = 0; r < 8; ++r)
      *(float4*)&red_sm[wv][r * 256 + ln * 4] = acc[r];
    __syncthreads();
    // reduce 8 ksegs for (row=wv, quad=ln)
    float4 z = make_float4(0.f, 0.f, 0.f, 0.f);
#pragma unroll
    for (int ks = 0; ks < 8; ++ks) {
      float4 p = *(const float4*)&red_sm[ks][wv * 256 + ln * 4];
      z.x += p.x; z.y += p.y; z.z += p.z; z.w += p.w;
    }
    float h_old = h_sm[wv][j];
    float h_out = h_old;
    if (t < len) {
      float ig = sigf(z.x + zx4.x + bias.x);
      float fg = sigf(z.y + zx4.y + bias.y);
      float gg = tanhfast(z.z + zx4.z + bias.z);
      float og = sigf(z.w + zx4.w + bias.w);
      c = fg * c + ig * gg;
      float hn = og * tanhfast(c);
      h_out = hn;
      omax = fmaxf(omax, hn);
    }
    if (s < TT - 1) {
      float* dst =
          hb + (size_t)(((((s + 1) & 1) * 2 + dir) * 256) + brow) * 256 + j;
      __hip_atomic_store(dst, h_out, __ATOMIC_RELAXED,
                         __HIP_MEMORY_SCOPE_AGENT);
      // prefetch next step's zx while stores drain / flag propagates
      const int tn = dir ? (TT - 2 - s) : (s + 1);
      float4 zxn = *(const float4*)(zx + (zxbase + tn) * 2048 + zxoff);
      asm volatile("s_waitcnt vmcnt(0)" ::: "memory");
      __syncthreads();  // all waves drained their h stores
      if (tid == 0) {
        __hip_atomic_fetch_add(ctr, 1u, __ATOMIC_RELAXED,
                               __HIP_MEMORY_SCOPE_AGENT);
      }
      const unsigned int target = 4u * (unsigned)(s + 1);
      while (__hip_atomic_load(ctr, __ATOMIC_RELAXED,
                               __HIP_MEMORY_SCOPE_AGENT) < target) {
      }
      asm volatile("" ::: "memory");  // no hoisting h loads above the spin
      zx4 = zxn;
    }
  }
  out[(size_t)brow * (2 * HD) + dir * HD + j] = omax;
}

// ---------------- fallback (round-1 fused step) if ws too small ------------
__global__ __launch_bounds__(256) void step_fused(
    const int* __restrict__ tok, const int* __restrict__ lens,
    const float* __restrict__ emb,
    const float* __restrict__ wih_f, const float* __restrict__ whh_f,
    const float* __restrict__ bias_f,
    const float* __restrict__ wih_b, const float* __restrict__ whh_b,
    const float* __restrict__ bias_b,
    float* __restrict__ ws, float* __restrict__ out, int s) {
  const int tid = threadIdx.x;
  const int jt = blockIdx.x, bt = blockIdx.y, dir = blockIdx.z;
  const int j0 = jt * 32, b0g = bt * 16;
  const int t = (dir == 0) ? s : (TT - 1 - s);
  const float* Wih = dir ? wih_b : wih_f;
  const float* Whh = dir ? whh_b : whh_f;
  const float* bias = dir ? bias_b : bias_f;
  const float* hcur = ws + OFF_H + (size_t)((s & 1) * 2 + dir) * BB * HD;
  float* hnxt = ws + OFF_H + (size_t)(((s + 1) & 1) * 2 + dir) * BB * HD;
  float* cbuf = ws + OFF_C + (size_t)dir * BB * HD;

  __shared__ float a_sm[16][64];
  __shared__ float w_sm[64][132];
  __shared__ float z_sm[16][132];

  const int cg = tid & 31, bg = tid >> 5;
  float acc[2][4] = {{0.f, 0.f, 0.f, 0.f}, {0.f, 0.f, 0.f, 0.f}};

  for (int phase = 0; phase < 2; ++phase) {
    const float* W = phase ? Whh : Wih;
    const int K = phase ? HD : EE;
    for (int k0 = 0; k0 < K; k0 += 64) {
      const int klen = (K - k0) < 64 ? (K - k0) : 64;
      {
        int bl = tid >> 4, kk4 = tid & 15;
        if (kk4 * 4 < klen) {
          const float* src;
          if (phase == 0) {
            int tk = tok[(b0g + bl) * TT + t];
            src = emb + (size_t)tk * EE + k0 + kk4 * 4;
          } else {
            src = hcur + (size_t)(b0g + bl) * HD + k0 + kk4 * 4;
          }
          *(float4*)&a_sm[bl][kk4 * 4] = *(const float4*)src;
        }
      }
      for (int i = 0; i < 8; ++i) {
        int e = i * 256 + tid;
        int col = e >> 4, kk4 = e & 15;
        if (kk4 * 4 < klen) {
          int gcol = ((col >> 5) * HD) + j0 + (col & 31);
          float4 v = *(const float4*)(W + (size_t)gcol * K + k0 + kk4 * 4);
          w_sm[kk4 * 4 + 0][col] = v.x;
          w_sm[kk4 * 4 + 1][col] = v.y;
          w_sm[kk4 * 4 + 2][col] = v.z;
          w_sm[kk4 * 4 + 3][col] = v.w;
        }
      }
      __syncthreads();
      for (int k = 0; k < klen; ++k) {
        float a0 = a_sm[bg * 2 + 0][k];
        float a1 = a_sm[bg * 2 + 1][k];
        float4 w = *(const float4*)&w_sm[k][cg * 4];
        acc[0][0] += a0 * w.x; acc[0][1] += a0 * w.y;
        acc[0][2] += a0 * w.z; acc[0][3] += a0 * w.w;
        acc[1][0] += a1 * w.x; acc[1][1] += a1 * w.y;
        acc[1][2] += a1 * w.z; acc[1][3] += a1 * w.w;
      }
      __syncthreads();
    }
  }
  *(float4*)&z_sm[bg * 2 + 0][cg * 4] =
      make_float4(acc[0][0], acc[0][1], acc[0][2], acc[0][3]);
  *(float4*)&z_sm[bg * 2 + 1][cg * 4] =
      make_float4(acc[1][0], acc[1][1], acc[1][2], acc[1][3]);
  __syncthreads();
  for (int pi = 0; pi < 2; ++pi) {
    int p = pi * 256 + tid;
    int bl = p >> 5, jl = p & 31;
    int bglob = b0g + bl, jglob = j0 + jl;
    bool valid = t < lens[bglob];
    float h_old = hcur[(size_t)bglob * HD + jglob];
    float h_out = h_old;
    if (valid) {
      float zi = z_sm[bl][0 + jl] + bias[0 * HD + jglob];
      float zf = z_sm[bl][32 + jl] + bias[1 * HD + jglob];
      float zg = z_sm[bl][64 + jl] + bias[2 * HD + jglob];
      float zo = z_sm[bl][96 + jl] + bias[3 * HD + jglob];
      float ig = sigf(zi), fg = sigf(zf), gg = tanhf(zg), og = sigf(zo);
      float c_old = cbuf[(size_t)bglob * HD + jglob];
      float c_new = fg * c_old + ig * gg;
      float h_new = og * tanhf(c_new);
      cbuf[(size_t)bglob * HD + jglob] = c_new;
      h_out = h_new;
      float* op = out + (size_t)bglob * (2 * HD) + dir * HD + jglob;
      *op = fmaxf(*op, h_new);
    }
    hnxt[(size_t)bglob * HD + jglob] = h_out;
  }
}

extern "C" void kernel_launch(void* const* d_in, const int* in_sizes, int n_in,
                              void* d_out, int out_size, void* d_ws,
                              size_t ws_size, hipStream_t stream) {
  const int* tok = (const int*)d_in[0];
  const int* lens = (const int*)d_in[1];
  const float* emb = (const float*)d_in[2];
  const float* wih_f = (const float*)d_in[3];
  const float* whh_f = (const float*)d_in[4];
  const float* b_f = (const float*)d_in[5];
  const float* wih_b = (const float*)d_in[6];
  const float* whh_b = (const float*)d_in[7];
  const float* b_b = (const float*)d_in[8];
  float* out = (float*)d_out;
  float* ws = (float*)d_ws;

  const bool full = ws_size >= WS_FULL_BYTES;
  if (full) {
    hipLaunchKernelGGL(prep_all, dim3(2560), dim3(256), 0, stream, whh_f,
                       whh_b, wih_f, wih_b, b_f, b_b, ws);
    hipLaunchKernelGGL(zx_mfma, dim3(256, 16), dim3(256), 0, stream, tok, emb,
                       ws);
    hipLaunchKernelGGL(lstm_persist, dim3(32, 4, 2), dim3(512), 0, stream,
                       lens, ws, out);
  } else {
    hipLaunchKernelGGL(init_kernel, dim3(1536), dim3(256), 0, stream, ws, out);
    for (int s = 0; s < TT; ++s) {
      hipLaunchKernelGGL(step_fused, dim3(8, 16, 2), dim3(256), 0, stream, tok,
                         lens, emb, wih_f, whh_f, b_f, wih_b, whh_b, b_b, ws,
                         out, s);
    }
  }
}

// Round 7
// 255.208 us; speedup vs baseline: 1.8120x; 1.8120x over previous
//
#include <hip/hip_runtime.h>
#include <hip/hip_bf16.h>
#include <math.h>

#define VV 50000
#define EE 300
#define HD 256
#define BB 256
#define TT 64
#define NEGV -1e9f

// ws layout (floats):
#define OFF_H    0         // [2 buf][2 dir][B][HD]      262144
#define OFF_C    262144    // fallback C-state; full path: padded barrier ctrs
#define OFF_CTR  262144    // [32 chains][32 u32] (128 B stride)
#define OFF_B2   393216    // [2 dir][1024] gate-interleaved bias   2048
#define OFF_WHHF 395264    // bf16 frags [dir][ngrp64][kt8][lane64][hi8|lo8] = 524288 fl
#define OFF_WIHB 919552    // bf16 [2048 n][320 k] = 327680 floats
#define OFF_ZX   1574912   // [(b*64+t)][2048] fp32               33554432
#define WS_FULL_BYTES ((35129344ULL + 64ULL) * 4ULL)

typedef __attribute__((ext_vector_type(8))) short bf16x8;
typedef __attribute__((ext_vector_type(4))) float f32x4;
typedef __attribute__((ext_vector_type(16))) float f32x16;

__device__ __forceinline__ float sigf(float x) {
  return 1.f / (1.f + __expf(-x));
}
__device__ __forceinline__ float tanhfast(float x) {
  return 1.f - 2.f / (__expf(2.f * x) + 1.f);
}
__device__ __forceinline__ unsigned short f2bf(float f) {
  union { float f; unsigned u; } x;
  x.f = f;
  unsigned r = x.u + 0x7fffu + ((x.u >> 16) & 1u);
  return (unsigned short)(r >> 16);
}

// ---------------- full-path prep: one kernel does everything ---------------
//   idx < 131072 : zero H buf0 (both dirs)
//   idx < 2048   : zero barrier counters + build gate-interleaved bias
//   idx < 65536  : W_hh -> bf16 hi/lo MFMA B-fragments
//   idx < 655360 : W_ih -> bf16 [n=dir*1024+j*4+g][k(320 pad)]
__global__ __launch_bounds__(256) void prep_all(
    const float* __restrict__ whf, const float* __restrict__ whb,
    const float* __restrict__ wif, const float* __restrict__ wib,
    const float* __restrict__ bf, const float* __restrict__ bb,
    float* __restrict__ ws) {
  int idx = blockIdx.x * 256 + threadIdx.x;
  if (idx < 131072) ws[OFF_H + idx] = 0.f;
  if (idx < 2048) {
    ((unsigned int*)(ws + OFF_CTR))[idx] = 0u;
    int dir = idx >> 10, jg = idx & 1023, j = jg >> 2, g = jg & 3;
    ws[OFF_B2 + idx] = (dir ? bb : bf)[g * HD + j];
  }
  if (idx < 65536) {
    // B-frag for mfma_f32_16x16x32_bf16: n = lane&15, k = kt*32+(lane>>4)*8+e
    int lane = idx & 63, kt = (idx >> 6) & 7, ngrp = (idx >> 9) & 63,
        dir = idx >> 15;
    int n = ngrp * 16 + (lane & 15);
    int j = n >> 2, g = n & 3;
    int k0 = kt * 32 + (lane >> 4) * 8;
    const float* W = dir ? whb : whf;
    const float* src = W + (size_t)((g << 8) + j) * HD + k0;
    union { unsigned short u[8]; uint4 q; } hp, lp;
#pragma unroll
    for (int e = 0; e < 8; ++e) {
      float v = src[e];
      unsigned short hh = f2bf(v);
      union { unsigned u; float f; } hf;
      hf.u = (unsigned)hh << 16;
      hp.u[e] = hh;
      lp.u[e] = f2bf(v - hf.f);
    }
    unsigned short* dst =
        (unsigned short*)(ws + OFF_WHHF) + (size_t)idx * 16;
    *(uint4*)dst = hp.q;
    *(uint4*)(dst + 8) = lp.q;
  }
  if (idx < 655360) {
    int n = idx / 320, k = idx - n * 320;
    int dir = n >> 10, jg = n & 1023, j = jg >> 2, g = jg & 3;
    float v = 0.f;
    if (k < EE) {
      const float* W = dir ? wib : wif;
      v = W[(size_t)((g << 8) + j) * EE + k];
    }
    ((unsigned short*)(ws + OFF_WIHB))[idx] = f2bf(v);
  }
}

// ---------------- fallback init ---------------------------------------------
__global__ __launch_bounds__(256) void init_kernel(float* __restrict__ ws,
                                                   float* __restrict__ out) {
  int idx = blockIdx.x * 256 + threadIdx.x;
  if (idx < 393216) ws[idx] = 0.f;
  if (idx < BB * 2 * HD) out[idx] = NEGV;
}

// ---------------- Zx = X @ WihT via bf16 MFMA 32x32x16 (round-5, verified) --
__global__ __launch_bounds__(256) void zx_mfma(const int* __restrict__ tok,
                                               const float* __restrict__ emb,
                                               float* __restrict__ ws) {
  __shared__ __align__(16) unsigned short a_sm[64 * 64];
  __shared__ __align__(16) unsigned short b_sm[128 * 64];
  const int tid = threadIdx.x;
  const int m0 = blockIdx.x * 64;
  const int n0 = blockIdx.y * 128;
  const unsigned short* wihb = (const unsigned short*)(ws + OFF_WIHB);
  float* zx = ws + OFF_ZX;
  const int lane = tid & 63;
  const int wv = tid >> 6;
  const int wm = wv >> 1, wn = wv & 1;

  f32x16 acc0, acc1;
#pragma unroll
  for (int i = 0; i < 16; ++i) { acc0[i] = 0.f; acc1[i] = 0.f; }

  const int sm_row = tid >> 2;
  const int sq = tid & 3;
  const int tokv = tok[m0 + sm_row];
  const float* er = emb + (size_t)tokv * EE;
  const int bn = tid >> 1;
  const int bq = tid & 1;
  const unsigned short* bsrc = wihb + (size_t)(n0 + bn) * 320 + bq * 32;

  const int fm = wm * 32 + (lane & 31);
  const int koc = lane >> 5;
  const int fnb = wn * 64 + (lane & 31);

  for (int kc = 0; kc < 5; ++kc) {
    const int k0 = kc * 64;
    {
      union { unsigned short u[8]; uint4 v; } pk;
#pragma unroll
      for (int c = 0; c < 2; ++c) {
#pragma unroll
        for (int e = 0; e < 8; ++e) {
          int k = k0 + sq * 16 + c * 8 + e;
          pk.u[e] = (k < EE) ? f2bf(er[k]) : (unsigned short)0;
        }
        int g = sq * 2 + c;
        int gs = g ^ (sm_row & 7);
        *(uint4*)&a_sm[sm_row * 64 + gs * 8] = pk.v;
      }
    }
    {
      const unsigned short* s = bsrc + k0;
#pragma unroll
      for (int c = 0; c < 4; ++c) {
        int g = bq * 4 + c;
        int gs = g ^ (bn & 7);
        *(uint4*)&b_sm[bn * 64 + gs * 8] = *(const uint4*)(s + c * 8);
      }
    }
    __syncthreads();
    bf16x8 afr[4];
#pragma unroll
    for (int ks = 0; ks < 4; ++ks) {
      int gs = (ks * 2 + koc) ^ (fm & 7);
      afr[ks] = *(const bf16x8*)&a_sm[fm * 64 + gs * 8];
    }
#pragma unroll
    for (int nf = 0; nf < 2; ++nf) {
      int n = fnb + nf * 32;
#pragma unroll
      for (int ks = 0; ks < 4; ++ks) {
        int gs = (ks * 2 + koc) ^ (n & 7);
        bf16x8 bfr = *(const bf16x8*)&b_sm[n * 64 + gs * 8];
        if (nf == 0)
          acc0 = __builtin_amdgcn_mfma_f32_32x32x16_bf16(afr[ks], bfr, acc0, 0, 0, 0);
        else
          acc1 = __builtin_amdgcn_mfma_f32_32x32x16_bf16(afr[ks], bfr, acc1, 0, 0, 0);
      }
    }
    __syncthreads();
  }
#pragma unroll
  for (int nf = 0; nf < 2; ++nf) {
#pragma unroll
    for (int r = 0; r < 16; ++r) {
      float v = (nf == 0) ? acc0[r] : acc1[r];
      int row = (r & 3) + 8 * (r >> 2) + 4 * (lane >> 5);
      int m = m0 + wm * 32 + row;
      int n = n0 + wn * 64 + nf * 32 + (lane & 31);
      zx[(size_t)m * 2048 + n] = v;
    }
  }
}

// ---------------- persistent recurrence: MFMA split-bf16, W frags resident --
// grid = (16 bgroup, 8 slice, 2 dir) x 512 threads, 1 block/CU.
// Per wave: 16-col jg tile; W = 8 kt x (hi,lo) bf16x8 frags (64 regs, AGPR-ok).
// z = Whi*hhi + Whi*hlo + Wlo*hhi  (fp32-grade).
__global__ __launch_bounds__(512) void lstm_persist(
    const int* __restrict__ lens, float* __restrict__ ws,
    float* __restrict__ out) {
  const int bg = blockIdx.x;     // 0..15 (16 batch rows)
  const int slice = blockIdx.y;  // 0..7  (128 jg = 32 j)
  const int dir = blockIdx.z;    // 0..1
  const int tid = threadIdx.x;
  const int lane = tid & 63;
  const int wv = tid >> 6;

  // A-frags: [part hi/lo][kt 8][chunk 68][8 bf16]; chunk = oct*17 + row
  __shared__ __align__(16) unsigned short afrag[8704];
  __shared__ float z_sm[16][132];

  bf16x8 whi[8], wlo[8];
  {
    const unsigned short* wb = (const unsigned short*)(ws + OFF_WHHF);
    const int ngrp = slice * 8 + wv;
    const unsigned short* p =
        wb + (size_t)(((dir * 64 + ngrp) * 8) * 64 + lane) * 16;
#pragma unroll
    for (int kt = 0; kt < 8; ++kt) {
      whi[kt] = *(const bf16x8*)(p + kt * 1024);
      wlo[kt] = *(const bf16x8*)(p + kt * 1024 + 8);
    }
  }

  const int rg = tid >> 5;  // row 0..15 (staging + gate)
  const int k8 = tid & 31;  // k-octet (staging)
  const int jl = tid & 31;  // j-local (gate)
  const int brow = bg * 16 + rg;
  const int len = lens[brow];
  const int j = slice * 32 + jl;
  const float4 bias =
      *(const float4*)(ws + OFF_B2 + dir * 1024 + slice * 128 + jl * 4);
  unsigned int* ctr =
      (unsigned int*)(ws + OFF_CTR) + (size_t)(dir * 16 + bg) * 32;
  const float* zx = ws + OFF_ZX;
  float* hb = ws + OFF_H;  // [2 buf][2 dir][256 b][256 j]
  const size_t zxbase = (size_t)brow * TT;
  const int zxoff = dir * 1024 + slice * 128 + jl * 4;

  float c = 0.f, omax = NEGV, h_prev = 0.f;
  float4 zx4 =
      *(const float4*)(zx + (zxbase + (dir ? TT - 1 : 0)) * 2048 + zxoff);

  const int st_chunk = (k8 & 3) * 17 + rg;        // + (k8>>2)*68
  const int st_kt = k8 >> 2;
  const int ld_r = lane & 15, ld_oct = lane >> 4;
  const int ld_chunk = ld_oct * 17 + ld_r;        // + kt*68

  for (int s = 0; s < TT; ++s) {
    const int t = dir ? (TT - 1 - s) : s;
    // ---- stage h(s) -> hi/lo bf16 A-frags in LDS ----
    {
      const unsigned long long* s8 = (const unsigned long long*)(
          hb + (size_t)(((s & 1) * 2 + dir) * 256 + brow) * 256 + k8 * 8);
      unsigned long long u0 =
          __hip_atomic_load(s8 + 0, __ATOMIC_RELAXED, __HIP_MEMORY_SCOPE_AGENT);
      unsigned long long u1 =
          __hip_atomic_load(s8 + 1, __ATOMIC_RELAXED, __HIP_MEMORY_SCOPE_AGENT);
      unsigned long long u2 =
          __hip_atomic_load(s8 + 2, __ATOMIC_RELAXED, __HIP_MEMORY_SCOPE_AGENT);
      unsigned long long u3 =
          __hip_atomic_load(s8 + 3, __ATOMIC_RELAXED, __HIP_MEMORY_SCOPE_AGENT);
      float v[8];
      __builtin_memcpy(&v[0], &u0, 8);
      __builtin_memcpy(&v[2], &u1, 8);
      __builtin_memcpy(&v[4], &u2, 8);
      __builtin_memcpy(&v[6], &u3, 8);
      union { unsigned short u[8]; uint4 q; } hp, lp;
#pragma unroll
      for (int e = 0; e < 8; ++e) {
        unsigned short hh = f2bf(v[e]);
        union { unsigned u; float f; } hf;
        hf.u = (unsigned)hh << 16;
        hp.u[e] = hh;
        lp.u[e] = f2bf(v[e] - hf.f);
      }
      int ch = st_kt * 68 + st_chunk;
      *(uint4*)(afrag + ch * 8) = hp.q;
      *(uint4*)(afrag + 4352 + ch * 8) = lp.q;
    }
    __syncthreads();
    // ---- MFMA: per wave z(16 rows x 16 cols), 4 acc chains ----
    f32x4 acc[4];
#pragma unroll
    for (int i = 0; i < 4; ++i) {
      acc[i][0] = 0.f; acc[i][1] = 0.f; acc[i][2] = 0.f; acc[i][3] = 0.f;
    }
#pragma unroll
    for (int kt = 0; kt < 8; ++kt) {
      int ch = kt * 68 + ld_chunk;
      bf16x8 ahi = *(const bf16x8*)(afrag + ch * 8);
      bf16x8 alo = *(const bf16x8*)(afrag + 4352 + ch * 8);
      f32x4 a = acc[kt & 3];
      a = __builtin_amdgcn_mfma_f32_16x16x32_bf16(ahi, whi[kt], a, 0, 0, 0);
      a = __builtin_amdgcn_mfma_f32_16x16x32_bf16(alo, whi[kt], a, 0, 0, 0);
      a = __builtin_amdgcn_mfma_f32_16x16x32_bf16(ahi, wlo[kt], a, 0, 0, 0);
      acc[kt & 3] = a;
    }
    f32x4 zf = (acc[0] + acc[1]) + (acc[2] + acc[3]);
    // D layout: col = lane&15, row = (lane>>4)*4 + i  (m89)
#pragma unroll
    for (int i = 0; i < 4; ++i)
      z_sm[ld_oct * 4 + i][wv * 16 + ld_r] = zf[i];
    __syncthreads();
    // ---- gates: thread owns (row rg, j) ----
    const float4 z4 = *(const float4*)&z_sm[rg][jl * 4];
    float h_out = h_prev;
    if (t < len) {
      float ig = sigf(z4.x + zx4.x + bias.x);
      float fg = sigf(z4.y + zx4.y + bias.y);
      float gg = tanhfast(z4.z + zx4.z + bias.z);
      float og = sigf(z4.w + zx4.w + bias.w);
      c = fg * c + ig * gg;
      float hn = og * tanhfast(c);
      h_out = hn;
      omax = fmaxf(omax, hn);
    }
    h_prev = h_out;
    if (s < TT - 1) {
      float* dst =
          hb + (size_t)(((((s + 1) & 1) * 2 + dir) * 256) + brow) * 256 + j;
      __hip_atomic_store(dst, h_out, __ATOMIC_RELAXED,
                         __HIP_MEMORY_SCOPE_AGENT);
      const int tn = dir ? (TT - 2 - s) : (s + 1);
      float4 zxn = *(const float4*)(zx + (zxbase + tn) * 2048 + zxoff);
      asm volatile("s_waitcnt vmcnt(0)" ::: "memory");
      __syncthreads();  // all waves drained h stores
      if (tid == 0) {
        __hip_atomic_fetch_add(ctr, 1u, __ATOMIC_RELAXED,
                               __HIP_MEMORY_SCOPE_AGENT);
      }
      if (tid < 64) {  // wave 0 spins (same-addr broadcast), others wait
        const unsigned int target = 8u * (unsigned)(s + 1);
        while (__hip_atomic_load(ctr, __ATOMIC_RELAXED,
                                 __HIP_MEMORY_SCOPE_AGENT) < target) {
        }
      }
      __syncthreads();
      asm volatile("" ::: "memory");
      zx4 = zxn;
    }
  }
  out[(size_t)brow * (2 * HD) + dir * HD + j] = omax;
}

// ---------------- fallback (round-1 fused step) if ws too small ------------
__global__ __launch_bounds__(256) void step_fused(
    const int* __restrict__ tok, const int* __restrict__ lens,
    const float* __restrict__ emb,
    const float* __restrict__ wih_f, const float* __restrict__ whh_f,
    const float* __restrict__ bias_f,
    const float* __restrict__ wih_b, const float* __restrict__ whh_b,
    const float* __restrict__ bias_b,
    float* __restrict__ ws, float* __restrict__ out, int s) {
  const int tid = threadIdx.x;
  const int jt = blockIdx.x, bt = blockIdx.y, dir = blockIdx.z;
  const int j0 = jt * 32, b0g = bt * 16;
  const int t = (dir == 0) ? s : (TT - 1 - s);
  const float* Wih = dir ? wih_b : wih_f;
  const float* Whh = dir ? whh_b : whh_f;
  const float* bias = dir ? bias_b : bias_f;
  const float* hcur = ws + OFF_H + (size_t)((s & 1) * 2 + dir) * BB * HD;
  float* hnxt = ws + OFF_H + (size_t)(((s + 1) & 1) * 2 + dir) * BB * HD;
  float* cbuf = ws + OFF_C + (size_t)dir * BB * HD;

  __shared__ float a_sm[16][64];
  __shared__ float w_sm[64][132];
  __shared__ float z_sm[16][132];

  const int cg = tid & 31, bg = tid >> 5;
  float acc[2][4] = {{0.f, 0.f, 0.f, 0.f}, {0.f, 0.f, 0.f, 0.f}};

  for (int phase = 0; phase < 2; ++phase) {
    const float* W = phase ? Whh : Wih;
    const int K = phase ? HD : EE;
    for (int k0 = 0; k0 < K; k0 += 64) {
      const int klen = (K - k0) < 64 ? (K - k0) : 64;
      {
        int bl = tid >> 4, kk4 = tid & 15;
        if (kk4 * 4 < klen) {
          const float* src;
          if (phase == 0) {
            int tk = tok[(b0g + bl) * TT + t];
            src = emb + (size_t)tk * EE + k0 + kk4 * 4;
          } else {
            src = hcur + (size_t)(b0g + bl) * HD + k0 + kk4 * 4;
          }
          *(float4*)&a_sm[bl][kk4 * 4] = *(const float4*)src;
        }
      }
      for (int i = 0; i < 8; ++i) {
        int e = i * 256 + tid;
        int col = e >> 4, kk4 = e & 15;
        if (kk4 * 4 < klen) {
          int gcol = ((col >> 5) * HD) + j0 + (col & 31);
          float4 v = *(const float4*)(W + (size_t)gcol * K + k0 + kk4 * 4);
          w_sm[kk4 * 4 + 0][col] = v.x;
          w_sm[kk4 * 4 + 1][col] = v.y;
          w_sm[kk4 * 4 + 2][col] = v.z;
          w_sm[kk4 * 4 + 3][col] = v.w;
        }
      }
      __syncthreads();
      for (int k = 0; k < klen; ++k) {
        float a0 = a_sm[bg * 2 + 0][k];
        float a1 = a_sm[bg * 2 + 1][k];
        float4 w = *(const float4*)&w_sm[k][cg * 4];
        acc[0][0] += a0 * w.x; acc[0][1] += a0 * w.y;
        acc[0][2] += a0 * w.z; acc[0][3] += a0 * w.w;
        acc[1][0] += a1 * w.x; acc[1][1] += a1 * w.y;
        acc[1][2] += a1 * w.z; acc[1][3] += a1 * w.w;
      }
      __syncthreads();
    }
  }
  *(float4*)&z_sm[bg * 2 + 0][cg * 4] =
      make_float4(acc[0][0], acc[0][1], acc[0][2], acc[0][3]);
  *(float4*)&z_sm[bg * 2 + 1][cg * 4] =
      make_float4(acc[1][0], acc[1][1], acc[1][2], acc[1][3]);
  __syncthreads();
  for (int pi = 0; pi < 2; ++pi) {
    int p = pi * 256 + tid;
    int bl = p >> 5, jl = p & 31;
    int bglob = b0g + bl, jglob = j0 + jl;
    bool valid = t < lens[bglob];
    float h_old = hcur[(size_t)bglob * HD + jglob];
    float h_out = h_old;
    if (valid) {
      float zi = z_sm[bl][0 + jl] + bias[0 * HD + jglob];
      float zf = z_sm[bl][32 + jl] + bias[1 * HD + jglob];
      float zg = z_sm[bl][64 + jl] + bias[2 * HD + jglob];
      float zo = z_sm[bl][96 + jl] + bias[3 * HD + jglob];
      float ig = sigf(zi), fg = sigf(zf), gg = tanhf(zg), og = sigf(zo);
      float c_old = cbuf[(size_t)bglob * HD + jglob];
      float c_new = fg * c_old + ig * gg;
      float h_new = og * tanhf(c_new);
      cbuf[(size_t)bglob * HD + jglob] = c_new;
      h_out = h_new;
      float* op = out + (size_t)bglob * (2 * HD) + dir * HD + jglob;
      *op = fmaxf(*op, h_new);
    }
    hnxt[(size_t)bglob * HD + jglob] = h_out;
  }
}

extern "C" void kernel_launch(void* const* d_in, const int* in_sizes, int n_in,
                              void* d_out, int out_size, void* d_ws,
                              size_t ws_size, hipStream_t stream) {
  const int* tok = (const int*)d_in[0];
  const int* lens = (const int*)d_in[1];
  const float* emb = (const float*)d_in[2];
  const float* wih_f = (const float*)d_in[3];
  const float* whh_f = (const float*)d_in[4];
  const float* b_f = (const float*)d_in[5];
  const float* wih_b = (const float*)d_in[6];
  const float* whh_b = (const float*)d_in[7];
  const float* b_b = (const float*)d_in[8];
  float* out = (float*)d_out;
  float* ws = (float*)d_ws;

  const bool full = ws_size >= WS_FULL_BYTES;
  if (full) {
    hipLaunchKernelGGL(prep_all, dim3(2560), dim3(256), 0, stream, whh_f,
                       whh_b, wih_f, wih_b, b_f, b_b, ws);
    hipLaunchKernelGGL(zx_mfma, dim3(256, 16), dim3(256), 0, stream, tok, emb,
                       ws);
    hipLaunchKernelGGL(lstm_persist, dim3(16, 8, 2), dim3(512), 0, stream,
                       lens, ws, out);
  } else {
    hipLaunchKernelGGL(init_kernel, dim3(1536), dim3(256), 0, stream, ws, out);
    for (int s = 0; s < TT; ++s) {
      hipLaunchKernelGGL(step_fused, dim3(8, 16, 2), dim3(256), 0, stream, tok,
                         lens, emb, wih_f, whh_f, b_f, wih_b, whh_b, b_b, ws,
                         out, s);
    }
  }
}

// Round 8
// 220.322 us; speedup vs baseline: 2.0990x; 1.1583x over previous
//
#include <hip/hip_runtime.h>
#include <hip/hip_bf16.h>
#include <math.h>

#define VV 50000
#define EE 300
#define HD 256
#define BB 256
#define TT 64
#define NEGV -1e9f

// ws layout (floats):
#define OFF_H    0         // [2 buf][2 dir][B][HD]      262144
#define OFF_C    262144    // fallback C-state; full path: padded barrier ctrs
#define OFF_CTR  262144    // [32 chains][32 u32] (128 B stride)
#define OFF_B2   393216    // [2 dir][1024] gate-interleaved bias   2048
#define OFF_WHHF 395264    // bf16 frags [dir][ngrp64][kt8][lane64][hi8|lo8] = 524288 fl
#define OFF_WIHF 919552    // bf16 frags [dir][ngrp64][kt10][lane64][8] = 327680 fl
#define WS_FULL_BYTES (1247232ULL * 4ULL)

typedef __attribute__((ext_vector_type(8))) short bf16x8;
typedef __attribute__((ext_vector_type(4))) float f32x4;

__device__ __forceinline__ float sigf(float x) {
  return 1.f / (1.f + __expf(-x));
}
__device__ __forceinline__ float tanhfast(float x) {
  return 1.f - 2.f / (__expf(2.f * x) + 1.f);
}
__device__ __forceinline__ unsigned short f2bf(float f) {
  union { float f; unsigned u; } x;
  x.f = f;
  unsigned r = x.u + 0x7fffu + ((x.u >> 16) & 1u);
  return (unsigned short)(r >> 16);
}

// ---------------- full-path prep ------------------------------------------
//   idx < 131072 : zero H buf0 (both dirs)
//   idx < 2048   : zero barrier counters + build gate-interleaved bias
//   idx < 65536  : W_hh -> bf16 hi/lo MFMA B-fragments (16x16x32, K=256)
//   idx < 81920  : W_ih -> bf16 MFMA B-fragments (K padded to 320)
__global__ __launch_bounds__(256) void prep_all(
    const float* __restrict__ whf, const float* __restrict__ whb,
    const float* __restrict__ wif, const float* __restrict__ wib,
    const float* __restrict__ bf, const float* __restrict__ bb,
    float* __restrict__ ws) {
  int idx = blockIdx.x * 256 + threadIdx.x;
  if (idx < 131072) ws[OFF_H + idx] = 0.f;
  if (idx < 2048) {
    ((unsigned int*)(ws + OFF_CTR))[idx] = 0u;
    int dir = idx >> 10, jg = idx & 1023, j = jg >> 2, g = jg & 3;
    ws[OFF_B2 + idx] = (dir ? bb : bf)[g * HD + j];
  }
  if (idx < 65536) {
    // frag (dir, ngrp, kt, lane): n = ngrp*16+(lane&15), k = kt*32+(lane>>4)*8+e
    int lane = idx & 63, kt = (idx >> 6) & 7, ngrp = (idx >> 9) & 63,
        dir = idx >> 15;
    int n = ngrp * 16 + (lane & 15);
    int j = n >> 2, g = n & 3;
    int k0 = kt * 32 + (lane >> 4) * 8;
    const float* W = dir ? whb : whf;
    const float* src = W + (size_t)((g << 8) + j) * HD + k0;
    union { unsigned short u[8]; uint4 q; } hp, lp;
#pragma unroll
    for (int e = 0; e < 8; ++e) {
      float v = src[e];
      unsigned short hh = f2bf(v);
      union { unsigned u; float f; } hf;
      hf.u = (unsigned)hh << 16;
      hp.u[e] = hh;
      lp.u[e] = f2bf(v - hf.f);
    }
    unsigned short* dst = (unsigned short*)(ws + OFF_WHHF) + (size_t)idx * 16;
    *(uint4*)dst = hp.q;
    *(uint4*)(dst + 8) = lp.q;
  }
  if (idx < 81920) {
    // frag id = ((dir*64 + ngrp)*10 + kt)*64 + lane
    int lane = idx & 63;
    int f = idx >> 6;
    int kt = f % 10;
    int ngrp = (f / 10) & 63;
    int dir = f / 640;
    int n = ngrp * 16 + (lane & 15);
    int j = n >> 2, g = n & 3;
    int k0 = kt * 32 + (lane >> 4) * 8;
    const float* W = dir ? wib : wif;
    union { unsigned short u[8]; uint4 q; } p;
#pragma unroll
    for (int e = 0; e < 8; ++e) {
      int k = k0 + e;
      p.u[e] = (k < EE) ? f2bf(W[(size_t)((g << 8) + j) * EE + k])
                        : (unsigned short)0;
    }
    *(uint4*)((unsigned short*)(ws + OFF_WIHF) + (size_t)idx * 8) = p.q;
  }
}

// ---------------- fallback init ---------------------------------------------
__global__ __launch_bounds__(256) void init_kernel(float* __restrict__ ws,
                                                   float* __restrict__ out) {
  int idx = blockIdx.x * 256 + threadIdx.x;
  if (idx < 393216) ws[idx] = 0.f;
  if (idx < BB * 2 * HD) out[idx] = NEGV;
}

// ---------------- persistent recurrence: fully fused (no Zx) ---------------
// grid = (16 bgroup, 8 slice, 2 dir) x 512 threads, 1 block/CU.
// Per wave resident: Whh hi/lo (16 frags) + Wih (10 frags) in AGPR/VGPR.
// Per step: z = Wih*x_t (bf16) + Whh_hi*h_hi + Whh_hi*h_lo + Whh_lo*h_hi.
// emb A-frags for t+1 staged one step ahead (double-buffered LDS).
// A-frag slot layout: slot = kt*64 + r*4 + oct  -> wave reads contiguous 1KB.
__global__ __launch_bounds__(512) void lstm_persist(
    const int* __restrict__ tok, const int* __restrict__ lens,
    const float* __restrict__ emb, float* __restrict__ ws,
    float* __restrict__ out) {
  const int bg = blockIdx.x;     // 0..15 (16 batch rows)
  const int slice = blockIdx.y;  // 0..7  (128 jg = 32 j)
  const int dir = blockIdx.z;    // 0..1
  const int tid = threadIdx.x;
  const int lane = tid & 63;
  const int wv = tid >> 6;

  __shared__ __align__(16) unsigned short hfr[8192];      // [hi|lo][kt8][slot64][8]
  __shared__ __align__(16) unsigned short ebuf[2][5120];  // [kt10][slot64][8]
  __shared__ float z_sm[16][132];

  // resident W fragments
  bf16x8 whi[8], wlo[8], wih[10];
  {
    const int ngrp = slice * 8 + wv;
    const unsigned short* p = (const unsigned short*)(ws + OFF_WHHF) +
                              (size_t)(((dir * 64 + ngrp) * 8) * 64 + lane) * 16;
#pragma unroll
    for (int kt = 0; kt < 8; ++kt) {
      whi[kt] = *(const bf16x8*)(p + kt * 1024);
      wlo[kt] = *(const bf16x8*)(p + kt * 1024 + 8);
    }
    const unsigned short* q = (const unsigned short*)(ws + OFF_WIHF) +
                              (size_t)(((dir * 64 + ngrp) * 10) * 64 + lane) * 8;
#pragma unroll
    for (int kt = 0; kt < 10; ++kt) wih[kt] = *(const bf16x8*)(q + kt * 512);
  }

  const int rg = tid >> 5;  // row 0..15 (staging + gate)
  const int k8 = tid & 31;  // k-octet (staging)
  const int jl = tid & 31;  // j-local (gate)
  const int brow = bg * 16 + rg;
  const int len = lens[brow];
  const int j = slice * 32 + jl;
  const float4 bias =
      *(const float4*)(ws + OFF_B2 + dir * 1024 + slice * 128 + jl * 4);
  unsigned int* ctr =
      (unsigned int*)(ws + OFF_CTR) + (size_t)(dir * 16 + bg) * 32;
  float* hb = ws + OFF_H;  // [2 buf][2 dir][256 b][256 j]
  const int ld_r = lane & 15, ld_oct = lane >> 4;
  const int trow = brow * TT;
  const int o2 = 32 + (k8 & 7);
  const bool has2 = (k8 < 8);
  const int slot1 = (k8 >> 2) * 64 + rg * 4 + (k8 & 3);          // octet k8
  const int slot2 = ((o2 >> 2) * 64) + rg * 4 + (o2 & 3);        // octet o2

  float c = 0.f, omax = NEGV, h_prev = 0.f;

  // ---- prologue: stage ebuf[0] for t(0) ----
  {
    const int t0 = dir ? (TT - 1) : 0;
    const float* er = emb + (size_t)tok[trow + t0] * EE;
    float4 a0 = *(const float4*)(er + k8 * 8);
    float4 a1 = *(const float4*)(er + k8 * 8 + 4);
    union { unsigned short u[8]; uint4 q; } p;
    p.u[0] = f2bf(a0.x); p.u[1] = f2bf(a0.y); p.u[2] = f2bf(a0.z);
    p.u[3] = f2bf(a0.w); p.u[4] = f2bf(a1.x); p.u[5] = f2bf(a1.y);
    p.u[6] = f2bf(a1.z); p.u[7] = f2bf(a1.w);
    *(uint4*)&ebuf[0][slot1 * 8] = p.q;
    if (has2) {
      float4 b0 = make_float4(0.f, 0.f, 0.f, 0.f);
      float4 b1 = make_float4(0.f, 0.f, 0.f, 0.f);
      if (o2 <= 37) b0 = *(const float4*)(er + o2 * 8);
      if (o2 < 37) b1 = *(const float4*)(er + o2 * 8 + 4);
      union { unsigned short u[8]; uint4 q; } p2;
      p2.u[0] = f2bf(b0.x); p2.u[1] = f2bf(b0.y); p2.u[2] = f2bf(b0.z);
      p2.u[3] = f2bf(b0.w); p2.u[4] = f2bf(b1.x); p2.u[5] = f2bf(b1.y);
      p2.u[6] = f2bf(b1.z); p2.u[7] = f2bf(b1.w);
      *(uint4*)&ebuf[0][slot2 * 8] = p2.q;
    }
  }

  for (int s = 0; s < TT; ++s) {
    const int t = dir ? (TT - 1 - s) : s;
    const bool nstage = (s < TT - 1);
    // ---- h(s) staging loads (coherent point loads) ----
    const unsigned long long* s8 = (const unsigned long long*)(
        hb + (size_t)(((s & 1) * 2 + dir) * 256 + brow) * 256 + k8 * 8);
    unsigned long long u0 =
        __hip_atomic_load(s8 + 0, __ATOMIC_RELAXED, __HIP_MEMORY_SCOPE_AGENT);
    unsigned long long u1 =
        __hip_atomic_load(s8 + 1, __ATOMIC_RELAXED, __HIP_MEMORY_SCOPE_AGENT);
    unsigned long long u2 =
        __hip_atomic_load(s8 + 2, __ATOMIC_RELAXED, __HIP_MEMORY_SCOPE_AGENT);
    unsigned long long u3 =
        __hip_atomic_load(s8 + 3, __ATOMIC_RELAXED, __HIP_MEMORY_SCOPE_AGENT);
    // ---- issue emb loads for t(s+1) (hidden under this step) ----
    float4 pe0, pe1, qe0, qe1;
    if (nstage) {
      const int tn = dir ? (TT - 2 - s) : (s + 1);
      const float* er = emb + (size_t)tok[trow + tn] * EE;
      pe0 = *(const float4*)(er + k8 * 8);
      pe1 = *(const float4*)(er + k8 * 8 + 4);
      qe0 = make_float4(0.f, 0.f, 0.f, 0.f);
      qe1 = make_float4(0.f, 0.f, 0.f, 0.f);
      if (has2) {
        if (o2 <= 37) qe0 = *(const float4*)(er + o2 * 8);
        if (o2 < 37) qe1 = *(const float4*)(er + o2 * 8 + 4);
      }
    }
    // ---- convert h -> hi/lo frags ----
    {
      float v[8];
      __builtin_memcpy(&v[0], &u0, 8);
      __builtin_memcpy(&v[2], &u1, 8);
      __builtin_memcpy(&v[4], &u2, 8);
      __builtin_memcpy(&v[6], &u3, 8);
      union { unsigned short u[8]; uint4 q; } hp, lp;
#pragma unroll
      for (int e = 0; e < 8; ++e) {
        unsigned short hh = f2bf(v[e]);
        union { unsigned u; float f; } hf;
        hf.u = (unsigned)hh << 16;
        hp.u[e] = hh;
        lp.u[e] = f2bf(v[e] - hf.f);
      }
      *(uint4*)&hfr[slot1 * 8] = hp.q;
      *(uint4*)&hfr[4096 + slot1 * 8] = lp.q;
    }
    __syncthreads();
    // ---- MFMA: 10 emb + 24 h (split) ----
    f32x4 acc[4];
#pragma unroll
    for (int i = 0; i < 4; ++i) {
      acc[i][0] = 0.f; acc[i][1] = 0.f; acc[i][2] = 0.f; acc[i][3] = 0.f;
    }
    const unsigned short* eb = ebuf[s & 1];
#pragma unroll
    for (int kt = 0; kt < 10; ++kt) {
      bf16x8 ax = *(const bf16x8*)(eb + (kt * 64 + ld_r * 4 + ld_oct) * 8);
      acc[kt & 3] =
          __builtin_amdgcn_mfma_f32_16x16x32_bf16(ax, wih[kt], acc[kt & 3], 0, 0, 0);
    }
#pragma unroll
    for (int kt = 0; kt < 8; ++kt) {
      const int sl = (kt * 64 + ld_r * 4 + ld_oct) * 8;
      bf16x8 ahi = *(const bf16x8*)(hfr + sl);
      bf16x8 alo = *(const bf16x8*)(hfr + 4096 + sl);
      f32x4 a = acc[kt & 3];
      a = __builtin_amdgcn_mfma_f32_16x16x32_bf16(ahi, whi[kt], a, 0, 0, 0);
      a = __builtin_amdgcn_mfma_f32_16x16x32_bf16(alo, whi[kt], a, 0, 0, 0);
      a = __builtin_amdgcn_mfma_f32_16x16x32_bf16(ahi, wlo[kt], a, 0, 0, 0);
      acc[kt & 3] = a;
    }
    f32x4 zf = (acc[0] + acc[1]) + (acc[2] + acc[3]);
    // D layout: col = lane&15, row = (lane>>4)*4 + i  (m89)
#pragma unroll
    for (int i = 0; i < 4; ++i)
      z_sm[ld_oct * 4 + i][wv * 16 + ld_r] = zf[i];
    __syncthreads();
    // ---- gates: thread owns (row rg, col j) ----
    const float4 z4 = *(const float4*)&z_sm[rg][jl * 4];
    float h_out = h_prev;
    if (t < len) {
      float ig = sigf(z4.x + bias.x);
      float fg = sigf(z4.y + bias.y);
      float gg = tanhfast(z4.z + bias.z);
      float og = sigf(z4.w + bias.w);
      c = fg * c + ig * gg;
      float hn = og * tanhfast(c);
      h_out = hn;
      omax = fmaxf(omax, hn);
    }
    h_prev = h_out;
    if (nstage) {
      float* dst =
          hb + (size_t)(((((s + 1) & 1) * 2 + dir) * 256) + brow) * 256 + j;
      __hip_atomic_store(dst, h_out, __ATOMIC_RELAXED,
                         __HIP_MEMORY_SCOPE_AGENT);
      // ---- convert prefetched emb -> ebuf[(s+1)&1] ----
      unsigned short* ebn = ebuf[(s + 1) & 1];
      {
        union { unsigned short u[8]; uint4 q; } p;
        p.u[0] = f2bf(pe0.x); p.u[1] = f2bf(pe0.y); p.u[2] = f2bf(pe0.z);
        p.u[3] = f2bf(pe0.w); p.u[4] = f2bf(pe1.x); p.u[5] = f2bf(pe1.y);
        p.u[6] = f2bf(pe1.z); p.u[7] = f2bf(pe1.w);
        *(uint4*)&ebn[slot1 * 8] = p.q;
        if (has2) {
          union { unsigned short u[8]; uint4 q; } p2;
          p2.u[0] = f2bf(qe0.x); p2.u[1] = f2bf(qe0.y); p2.u[2] = f2bf(qe0.z);
          p2.u[3] = f2bf(qe0.w); p2.u[4] = f2bf(qe1.x); p2.u[5] = f2bf(qe1.y);
          p2.u[6] = f2bf(qe1.z); p2.u[7] = f2bf(qe1.w);
          *(uint4*)&ebn[slot2 * 8] = p2.q;
        }
      }
      asm volatile("s_waitcnt vmcnt(0)" ::: "memory");
      __syncthreads();  // all waves drained h stores
      if (tid == 0) {
        __hip_atomic_fetch_add(ctr, 1u, __ATOMIC_RELAXED,
                               __HIP_MEMORY_SCOPE_AGENT);
      }
      if (tid < 64) {  // wave 0 spins (same-addr broadcast), others wait
        const unsigned int target = 8u * (unsigned)(s + 1);
        while (__hip_atomic_load(ctr, __ATOMIC_RELAXED,
                                 __HIP_MEMORY_SCOPE_AGENT) < target) {
        }
      }
      __syncthreads();
      asm volatile("" ::: "memory");
    }
  }
  out[(size_t)brow * (2 * HD) + dir * HD + j] = omax;
}

// ---------------- fallback (round-1 fused step) if ws too small ------------
__global__ __launch_bounds__(256) void step_fused(
    const int* __restrict__ tok, const int* __restrict__ lens,
    const float* __restrict__ emb,
    const float* __restrict__ wih_f, const float* __restrict__ whh_f,
    const float* __restrict__ bias_f,
    const float* __restrict__ wih_b, const float* __restrict__ whh_b,
    const float* __restrict__ bias_b,
    float* __restrict__ ws, float* __restrict__ out, int s) {
  const int tid = threadIdx.x;
  const int jt = blockIdx.x, bt = blockIdx.y, dir = blockIdx.z;
  const int j0 = jt * 32, b0g = bt * 16;
  const int t = (dir == 0) ? s : (TT - 1 - s);
  const float* Wih = dir ? wih_b : wih_f;
  const float* Whh = dir ? whh_b : whh_f;
  const float* bias = dir ? bias_b : bias_f;
  const float* hcur = ws + OFF_H + (size_t)((s & 1) * 2 + dir) * BB * HD;
  float* hnxt = ws + OFF_H + (size_t)(((s + 1) & 1) * 2 + dir) * BB * HD;
  float* cbuf = ws + OFF_C + (size_t)dir * BB * HD;

  __shared__ float a_sm[16][64];
  __shared__ float w_sm[64][132];
  __shared__ float z_sm[16][132];

  const int cg = tid & 31, bg = tid >> 5;
  float acc[2][4] = {{0.f, 0.f, 0.f, 0.f}, {0.f, 0.f, 0.f, 0.f}};

  for (int phase = 0; phase < 2; ++phase) {
    const float* W = phase ? Whh : Wih;
    const int K = phase ? HD : EE;
    for (int k0 = 0; k0 < K; k0 += 64) {
      const int klen = (K - k0) < 64 ? (K - k0) : 64;
      {
        int bl = tid >> 4, kk4 = tid & 15;
        if (kk4 * 4 < klen) {
          const float* src;
          if (phase == 0) {
            int tk = tok[(b0g + bl) * TT + t];
            src = emb + (size_t)tk * EE + k0 + kk4 * 4;
          } else {
            src = hcur + (size_t)(b0g + bl) * HD + k0 + kk4 * 4;
          }
          *(float4*)&a_sm[bl][kk4 * 4] = *(const float4*)src;
        }
      }
      for (int i = 0; i < 8; ++i) {
        int e = i * 256 + tid;
        int col = e >> 4, kk4 = e & 15;
        if (kk4 * 4 < klen) {
          int gcol = ((col >> 5) * HD) + j0 + (col & 31);
          float4 v = *(const float4*)(W + (size_t)gcol * K + k0 + kk4 * 4);
          w_sm[kk4 * 4 + 0][col] = v.x;
          w_sm[kk4 * 4 + 1][col] = v.y;
          w_sm[kk4 * 4 + 2][col] = v.z;
          w_sm[kk4 * 4 + 3][col] = v.w;
        }
      }
      __syncthreads();
      for (int k = 0; k < klen; ++k) {
        float a0 = a_sm[bg * 2 + 0][k];
        float a1 = a_sm[bg * 2 + 1][k];
        float4 w = *(const float4*)&w_sm[k][cg * 4];
        acc[0][0] += a0 * w.x; acc[0][1] += a0 * w.y;
        acc[0][2] += a0 * w.z; acc[0][3] += a0 * w.w;
        acc[1][0] += a1 * w.x; acc[1][1] += a1 * w.y;
        acc[1][2] += a1 * w.z; acc[1][3] += a1 * w.w;
      }
      __syncthreads();
    }
  }
  *(float4*)&z_sm[bg * 2 + 0][cg * 4] =
      make_float4(acc[0][0], acc[0][1], acc[0][2], acc[0][3]);
  *(float4*)&z_sm[bg * 2 + 1][cg * 4] =
      make_float4(acc[1][0], acc[1][1], acc[1][2], acc[1][3]);
  __syncthreads();
  for (int pi = 0; pi < 2; ++pi) {
    int p = pi * 256 + tid;
    int bl = p >> 5, jl = p & 31;
    int bglob = b0g + bl, jglob = j0 + jl;
    bool valid = t < lens[bglob];
    float h_old = hcur[(size_t)bglob * HD + jglob];
    float h_out = h_old;
    if (valid) {
      float zi = z_sm[bl][0 + jl] + bias[0 * HD + jglob];
      float zf = z_sm[bl][32 + jl] + bias[1 * HD + jglob];
      float zg = z_sm[bl][64 + jl] + bias[2 * HD + jglob];
      float zo = z_sm[bl][96 + jl] + bias[3 * HD + jglob];
      float ig = sigf(zi), fg = sigf(zf), gg = tanhf(zg), og = sigf(zo);
      float c_old = cbuf[(size_t)bglob * HD + jglob];
      float c_new = fg * c_old + ig * gg;
      float h_new = og * tanhf(c_new);
      cbuf[(size_t)bglob * HD + jglob] = c_new;
      h_out = h_new;
      float* op = out + (size_t)bglob * (2 * HD) + dir * HD + jglob;
      *op = fmaxf(*op, h_new);
    }
    hnxt[(size_t)bglob * HD + jglob] = h_out;
  }
}

extern "C" void kernel_launch(void* const* d_in, const int* in_sizes, int n_in,
                              void* d_out, int out_size, void* d_ws,
                              size_t ws_size, hipStream_t stream) {
  const int* tok = (const int*)d_in[0];
  const int* lens = (const int*)d_in[1];
  const float* emb = (const float*)d_in[2];
  const float* wih_f = (const float*)d_in[3];
  const float* whh_f = (const float*)d_in[4];
  const float* b_f = (const float*)d_in[5];
  const float* wih_b = (const float*)d_in[6];
  const float* whh_b = (const float*)d_in[7];
  const float* b_b = (const float*)d_in[8];
  float* out = (float*)d_out;
  float* ws = (float*)d_ws;

  const bool full = ws_size >= WS_FULL_BYTES;
  if (full) {
    hipLaunchKernelGGL(prep_all, dim3(512), dim3(256), 0, stream, whh_f,
                       whh_b, wih_f, wih_b, b_f, b_b, ws);
    hipLaunchKernelGGL(lstm_persist, dim3(16, 8, 2), dim3(512), 0, stream,
                       tok, lens, emb, ws, out);
  } else {
    hipLaunchKernelGGL(init_kernel, dim3(1536), dim3(256), 0, stream, ws, out);
    for (int s = 0; s < TT; ++s) {
      hipLaunchKernelGGL(step_fused, dim3(8, 16, 2), dim3(256), 0, stream, tok,
                         lens, emb, wih_f, whh_f, b_f, wih_b, whh_b, b_b, ws,
                         out, s);
    }
  }
}